// Round 3
// baseline (692.102 us; speedup 1.0000x reference)
//
#include <hip/hip_runtime.h>

#define N_TOK 8192
#define DIM   1024
#define HID   2048
#define NEXP  8
#define TOPK  2
#define BM 128
#define BN 256
#define BK 64
#define NTHREADS 512
#define MAXROWS (N_TOK*TOPK + NEXP*BM)   /* 17408 */
#define MAXRT   (MAXROWS/BM)             /* 136 row tiles */
#define NT_COL  (HID/BN)                 /* 8 col tiles */

typedef float f32x4 __attribute__((ext_vector_type(4)));
typedef short bf16x8 __attribute__((ext_vector_type(8)));

static __device__ __forceinline__ unsigned short f2bf(float f){
    union { float f; unsigned u; } v; v.f = f;
    unsigned r = v.u + 0x7FFFu + ((v.u >> 16) & 1u);
    return (unsigned short)(r >> 16);
}
static __device__ __forceinline__ float bf2f(unsigned short u){
    union { unsigned u; float f; } v; v.u = ((unsigned)u) << 16;
    return v.f;
}

static __device__ __forceinline__ void gload_lds16(const void* g, void* l){
    __builtin_amdgcn_global_load_lds((const __attribute__((address_space(1))) void*)g,
                                     (__attribute__((address_space(3))) void*)l,
                                     16, 0, 0);
}

// ---------------- weight convert + transpose (coalesced writes):
// src [z][R][C] f32 -> dst [z][C][R] bf16; 64x64 tiles, 256 threads
__global__ __launch_bounds__(256) void cvt_transpose_moe(
    const float* __restrict__ src, unsigned short* __restrict__ dst, int R, int C)
{
    __shared__ float tile[64][65];
    const size_t plane = (size_t)R * C;
    const float* s = src + (size_t)blockIdx.z * plane;
    unsigned short* d = dst + (size_t)blockIdx.z * plane;
    const int c0 = blockIdx.x * 64, r0 = blockIdx.y * 64;
    const int tq = threadIdx.x & 15, tr = threadIdx.x >> 4;   // 16 x 16
    #pragma unroll
    for (int p = 0; p < 4; ++p) {
        int row = p*16 + tr;
        float4 v = *(const float4*)(s + (size_t)(r0 + row) * C + c0 + tq*4);
        tile[row][tq*4+0] = v.x; tile[row][tq*4+1] = v.y;
        tile[row][tq*4+2] = v.z; tile[row][tq*4+3] = v.w;
    }
    __syncthreads();
    #pragma unroll
    for (int p = 0; p < 4; ++p) {
        int orow = p*16 + tr;          // C-dim index
        ushort4 o;
        o.x = f2bf(tile[tq*4+0][orow]);
        o.y = f2bf(tile[tq*4+1][orow]);
        o.z = f2bf(tile[tq*4+2][orow]);
        o.w = f2bf(tile[tq*4+3][orow]);
        *(ushort4*)(d + (size_t)(c0 + orow) * R + r0 + tq*4) = o;
    }
}

// ---------------- router: 1 wave per token
__global__ __launch_bounds__(256) void router_moe(
    const float* __restrict__ x, const float* __restrict__ Wg, const float* __restrict__ bg,
    float* __restrict__ gate_probs, float* __restrict__ gate_mask,
    int* __restrict__ tk_e, float* __restrict__ tk_w, int* __restrict__ counts)
{
    const int lane = threadIdx.x & 63;
    const int n = blockIdx.x * 4 + (threadIdx.x >> 6);
    const float* xr = x + (size_t)n * DIM;

    float acc[NEXP];
    #pragma unroll
    for (int e = 0; e < NEXP; ++e) acc[e] = 0.f;
    #pragma unroll 4
    for (int i = 0; i < DIM/64; ++i) {
        int d = i*64 + lane;
        float xv = xr[d];
        const float4* wrow = (const float4*)(Wg + (size_t)d * NEXP);
        float4 w0 = wrow[0], w1 = wrow[1];
        acc[0] += xv*w0.x; acc[1] += xv*w0.y; acc[2] += xv*w0.z; acc[3] += xv*w0.w;
        acc[4] += xv*w1.x; acc[5] += xv*w1.y; acc[6] += xv*w1.z; acc[7] += xv*w1.w;
    }
    #pragma unroll
    for (int off = 32; off > 0; off >>= 1) {
        #pragma unroll
        for (int e = 0; e < NEXP; ++e) acc[e] += __shfl_xor(acc[e], off, 64);
    }
    float lgt[NEXP];
    float mx = acc[0] + bg[0];
    #pragma unroll
    for (int e = 0; e < NEXP; ++e) { lgt[e] = acc[e] + bg[e]; mx = fmaxf(mx, lgt[e]); }
    float s = 0.f;
    #pragma unroll
    for (int e = 0; e < NEXP; ++e) { lgt[e] = expf(lgt[e] - mx); s += lgt[e]; }
    float inv = 1.f / s;
    #pragma unroll
    for (int e = 0; e < NEXP; ++e) lgt[e] *= inv;   // probs

    int i1 = 0;
    #pragma unroll
    for (int e = 1; e < NEXP; ++e) if (lgt[e] > lgt[i1]) i1 = e;
    int i2 = (i1 == 0) ? 1 : 0;
    #pragma unroll
    for (int e = 0; e < NEXP; ++e) if (e != i1 && lgt[e] > lgt[i2]) i2 = e;
    float wsum = lgt[i1] + lgt[i2] + 1e-8f;
    float w1n = lgt[i1] / wsum, w2n = lgt[i2] / wsum;

    if (lane < NEXP) {
        gate_probs[(size_t)n*NEXP + lane] = lgt[lane];
        gate_mask [(size_t)n*NEXP + lane] = (lane == i1) ? w1n : (lane == i2) ? w2n : 0.f;
    }
    if (lane == 0) {
        tk_e[n*TOPK]   = i1; tk_e[n*TOPK+1] = i2;
        tk_w[n*TOPK]   = w1n; tk_w[n*TOPK+1] = w2n;
        atomicAdd(&counts[i1], 1);
        atomicAdd(&counts[i2], 1);
    }
}

// ---------------- scan: bases, cursors, tile schedule
__global__ void scan_moe(const int* __restrict__ counts, int* __restrict__ bases,
                         int* __restrict__ cursors, int* __restrict__ sched_e,
                         int* __restrict__ sched_row, int* __restrict__ total_tiles)
{
    if (threadIdx.x != 0 || blockIdx.x != 0) return;
    int base = 0, t = 0;
    for (int e = 0; e < NEXP; ++e) {
        bases[e] = base; cursors[e] = 0;
        int nt = (counts[e] + BM - 1) / BM;
        for (int i = 0; i < nt; ++i) { sched_e[t] = e; sched_row[t] = base + i*BM; ++t; }
        base += nt * BM;
    }
    *total_tiles = t;
}

// ---------------- gather: token rows -> expert-grouped bf16 rows
// pair_token[r] = n*2 + slot  (-1 for pad rows)
__global__ __launch_bounds__(256) void gather_moe(
    const float* __restrict__ x, const int* __restrict__ tk_e,
    const int* __restrict__ bases, int* __restrict__ cursors,
    unsigned short* __restrict__ Xg, int* __restrict__ pair_token)
{
    __shared__ int rows_s[TOPK];
    const int n = blockIdx.x;
    if (threadIdx.x < TOPK) {
        int e = tk_e[n*TOPK + threadIdx.x];
        int slot = atomicAdd(&cursors[e], 1);
        int r = bases[e] + slot;
        rows_s[threadIdx.x] = r;
        pair_token[r] = n*2 + threadIdx.x;
    }
    __syncthreads();
    float4 xv = ((const float4*)(x + (size_t)n * DIM))[threadIdx.x];
    ushort4 b;
    b.x = f2bf(xv.x); b.y = f2bf(xv.y); b.z = f2bf(xv.z); b.w = f2bf(xv.w);
    #pragma unroll
    for (int kk = 0; kk < TOPK; ++kk)
        ((ushort4*)(Xg + (size_t)rows_s[kk] * DIM))[threadIdx.x] = b;
}

// ---------------- grouped GEMM: 128x256 tile, BK=64, 8 waves (64x64 each),
// 2-phase/K-tile schedule, front-loaded staging, aged vmcnt(0) drain at tile end.
// MODE 0: Out = relu(A @ Bt^T + bias) -> bf16, linear rows (Hb)
// MODE 1: P[pair] = A @ Bt^T + bias   -> bf16, token-slot scatter (no atomics)
template<int K, int MODE>
__global__ __launch_bounds__(512, 1) void gemm_moe(
    const unsigned short* __restrict__ A,    // [rows][K] bf16
    const unsigned short* __restrict__ Bt,   // [E][HID][K] bf16
    const float* __restrict__ bias,          // [E][HID]
    const int* __restrict__ sched_e, const int* __restrict__ sched_row,
    const int* __restrict__ total_tiles,
    unsigned short* __restrict__ Out,
    const int* __restrict__ pair_token)
{
    // T1: bijective XCD swizzle over the linear grid (1088 % 8 == 0)
    const int nwg  = gridDim.x * gridDim.y;
    const int orig = blockIdx.y * gridDim.x + blockIdx.x;
    const int q = nwg >> 3, r8 = nwg & 7, xcd = orig & 7, lin = orig >> 3;
    const int wg = (xcd < r8 ? xcd*(q+1) : r8*(q+1) + (xcd-r8)*q) + lin;
    const int rt = wg / NT_COL, ct = wg % NT_COL;
    if (rt >= *total_tiles) return;

    const int e    = sched_e[rt];
    const int row0 = sched_row[rt];
    const int col0 = ct * BN;
    const unsigned short* Be = Bt + (size_t)e * HID * K;

    __shared__ __align__(1024) char lds[98304];    // 2 bufs x (A 16KB + B 32KB)

    const int tid  = threadIdx.x;
    const int wv   = tid >> 6, lane = tid & 63;
    const int wr   = wv >> 2,  wc   = wv & 3;      // 2 x 4 wave grid, wave = 64x64
    const int lrow = lane & 15, lg  = lane >> 4;
    const int sr   = lane >> 3, si  = lane & 7;
    const int gc16 = si ^ sr;                      // pre-swizzled global 16B slot (T2)

    const unsigned short* Ab = A  + (size_t)row0 * K + gc16 * 8;
    const unsigned short* Bb = Be + (size_t)col0 * K + gc16 * 8;

    f32x4 acc[4][4] = {};

    auto STAGE_A = [&](char* Ad, int k0) {         // 16 chunks: rows 0..127
        #pragma unroll
        for (int j = 0; j < 2; ++j) {
            int chunk = wv*2 + j;
            gload_lds16(Ab + (size_t)(chunk*8 + sr) * K + k0, Ad + chunk*1024);
        }
    };
    auto STAGE_B = [&](char* Bd, int k0, int jb) { // 32 chunks: cols 0..255
        #pragma unroll
        for (int j = 0; j < 2; ++j) {
            int chunk = wv*4 + jb + j;
            gload_lds16(Bb + (size_t)(chunk*8 + sr) * K + k0, Bd + chunk*1024);
        }
    };

    bf16x8 af[4], bfr[4];
    auto LOADFRAGS = [&](const char* Al, const char* Bl, int kk) {
        #pragma unroll
        for (int m = 0; m < 4; ++m) {
            int r = wr*64 + m*16 + lrow;
            int c16 = (kk*4 + lg) ^ (r & 7);
            af[m] = *(const bf16x8*)(Al + r*128 + c16*16);
        }
        #pragma unroll
        for (int nb = 0; nb < 4; ++nb) {
            int r = wc*64 + nb*16 + lrow;
            int c16 = (kk*4 + lg) ^ (r & 7);
            bfr[nb] = *(const bf16x8*)(Bl + r*128 + c16*16);
        }
    };
    auto MFMA16 = [&]() {
        __builtin_amdgcn_s_setprio(1);
        #pragma unroll
        for (int m = 0; m < 4; ++m)
            #pragma unroll
            for (int nb = 0; nb < 4; ++nb)
                acc[m][nb] = __builtin_amdgcn_mfma_f32_16x16x32_bf16(
                                 af[m], bfr[nb], acc[m][nb], 0, 0, 0);
        __builtin_amdgcn_s_setprio(0);
    };
    auto BAR = [&]() {
        __builtin_amdgcn_sched_barrier(0);
        __builtin_amdgcn_s_barrier();
        __builtin_amdgcn_sched_barrier(0);
    };

    constexpr int NT = K / BK;
    // prologue: stage tile 0 fully, drain, sync
    {
        char* Ad = lds; char* Bd = lds + 16384;
        STAGE_A(Ad, 0); STAGE_B(Bd, 0, 0); STAGE_B(Bd, 0, 2);
    }
    asm volatile("s_waitcnt vmcnt(0)" ::: "memory");
    BAR();

    int cur = 0;
    for (int t = 0; t < NT; ++t) {
        const char* Al = lds + cur*49152;
        const char* Bl = Al + 16384;
        char* Ad = lds + (cur^1)*49152;
        char* Bd = Ad + 16384;
        const bool pf = (t + 1 < NT);
        const int kn = (t + 1) * BK;

        // phase 1: k-step 0
        LOADFRAGS(Al, Bl, 0);
        if (pf) { STAGE_A(Ad, kn); STAGE_B(Bd, kn, 0); }   // HBM-critical A first
        BAR();
        MFMA16();
        BAR();

        // phase 2: k-step 1
        LOADFRAGS(Al, Bl, 1);
        if (pf) STAGE_B(Bd, kn, 2);
        BAR();
        MFMA16();
        // tile-end: drain staging loads (aged 1-2 phases), then sync
        asm volatile("s_waitcnt vmcnt(0)" ::: "memory");
        BAR();
        cur ^= 1;
    }

    // epilogue: C/D layout col=lane&15, row=(lane>>4)*4+reg
    if constexpr (MODE == 0) {
        #pragma unroll
        for (int nb = 0; nb < 4; ++nb) {
            int col = col0 + wc*64 + nb*16 + lrow;
            float bv = bias[(size_t)e*HID + col];
            #pragma unroll
            for (int mb = 0; mb < 4; ++mb) {
                int rb = row0 + wr*64 + mb*16 + lg*4;
                #pragma unroll
                for (int j = 0; j < 4; ++j) {
                    float v = fmaxf(acc[mb][nb][j] + bv, 0.f);
                    Out[(size_t)(rb + j) * HID + col] = f2bf(v);
                }
            }
        }
    } else {
        float bv[4]; int cols[4];
        #pragma unroll
        for (int nb = 0; nb < 4; ++nb) {
            cols[nb] = col0 + wc*64 + nb*16 + lrow;
            bv[nb] = bias[(size_t)e*HID + cols[nb]];
        }
        #pragma unroll
        for (int mb = 0; mb < 4; ++mb) {
            #pragma unroll
            for (int j = 0; j < 4; ++j) {
                int r = row0 + wr*64 + mb*16 + lg*4 + j;
                int pair = pair_token[r];
                if (pair < 0) continue;            // pad row
                size_t prow = (size_t)(pair & 1) * N_TOK + (pair >> 1);
                #pragma unroll
                for (int nb = 0; nb < 4; ++nb)
                    Out[prow * HID + cols[nb]] = f2bf(acc[mb][nb][j] + bv[nb]);
            }
        }
    }
}

// ---------------- combine: out[n] = w0*P[0][n] + w1*P[1][n]
__global__ __launch_bounds__(256) void combine_moe(
    const unsigned short* __restrict__ P, const float* __restrict__ tk_w,
    float* __restrict__ out)
{
    const int n = blockIdx.x;
    const float w0 = tk_w[n*2], w1 = tk_w[n*2+1];
    const int c = threadIdx.x * 8;
    bf16x8 a = *(const bf16x8*)(P + (size_t)n * HID + c);
    bf16x8 b = *(const bf16x8*)(P + (size_t)(N_TOK + n) * HID + c);
    float4 o0, o1;
    float* op = &o0.x;
    #pragma unroll
    for (int i = 0; i < 4; ++i)
        op[i] = w0 * bf2f((unsigned short)a[i]) + w1 * bf2f((unsigned short)b[i]);
    float* op1 = &o1.x;
    #pragma unroll
    for (int i = 0; i < 4; ++i)
        op1[i] = w0 * bf2f((unsigned short)a[4+i]) + w1 * bf2f((unsigned short)b[4+i]);
    float4* dst = (float4*)(out + (size_t)n * HID + c);
    dst[0] = o0; dst[1] = o1;
}

extern "C" void kernel_launch(void* const* d_in, const int* in_sizes, int n_in,
                              void* d_out, int out_size, void* d_ws, size_t ws_size,
                              hipStream_t stream)
{
    const float* x  = (const float*)d_in[0];
    const float* Wg = (const float*)d_in[1];
    const float* bg = (const float*)d_in[2];
    const float* W1 = (const float*)d_in[3];
    const float* b1 = (const float*)d_in[4];
    const float* W2 = (const float*)d_in[5];
    const float* b2 = (const float*)d_in[6];

    float* out        = (float*)d_out;                       // [N, HID]
    float* gate_probs = out + (size_t)N_TOK * HID;           // [N, E]
    float* gate_mask  = gate_probs + (size_t)N_TOK * NEXP;   // [N, E]

    // workspace carve; P aliases dead W1t+Xg after GEMM1
    char* p = (char*)d_ws;
    auto carve = [&](size_t bytes) { char* r = p; p += (bytes + 255) & ~(size_t)255; return r; };
    unsigned short* W2t = (unsigned short*)carve((size_t)NEXP*HID*HID*2);  // 64 MB [e][j][h]
    unsigned short* Hb  = (unsigned short*)carve((size_t)MAXROWS*HID*2);   // 71 MB
    unsigned short* W1t = (unsigned short*)carve((size_t)NEXP*DIM*HID*2);  // 32 MB [e][h][d]
    unsigned short* Xg  = (unsigned short*)carve((size_t)MAXROWS*DIM*2);   // 36 MB
    unsigned short* P   = W1t;   // 64 MB alias over W1t(32)+Xg(36); both dead at GEMM2
    int*   pair_token = (int*)  carve((size_t)MAXROWS*4);
    int*   tk_e       = (int*)  carve((size_t)N_TOK*TOPK*4);
    float* tk_w       = (float*)carve((size_t)N_TOK*TOPK*4);
    int*   counts     = (int*)  carve(256);
    int*   bases      = (int*)  carve(256);
    int*   cursors    = (int*)  carve(256);
    int*   sched_e    = (int*)  carve(1024);
    int*   sched_row  = (int*)  carve(1024);
    int*   total_tiles= (int*)  carve(256);

    hipMemsetAsync(counts, 0, 256, stream);
    hipMemsetAsync(pair_token, 0xFF, (size_t)MAXROWS*4, stream);  // -1 = pad

    cvt_transpose_moe<<<dim3(HID/64, DIM/64, NEXP), 256, 0, stream>>>(W1, W1t, DIM, HID);
    cvt_transpose_moe<<<dim3(HID/64, HID/64, NEXP), 256, 0, stream>>>(W2, W2t, HID, HID);
    router_moe<<<N_TOK/4, 256, 0, stream>>>(x, Wg, bg, gate_probs, gate_mask, tk_e, tk_w, counts);
    scan_moe<<<1, 64, 0, stream>>>(counts, bases, cursors, sched_e, sched_row, total_tiles);
    gather_moe<<<N_TOK, 256, 0, stream>>>(x, tk_e, bases, cursors, Xg, pair_token);
    gemm_moe<DIM, 0><<<dim3(MAXRT, NT_COL), NTHREADS, 0, stream>>>(
        Xg, W1t, b1, sched_e, sched_row, total_tiles, Hb, nullptr);
    gemm_moe<HID, 1><<<dim3(MAXRT, NT_COL), NTHREADS, 0, stream>>>(
        Hb, W2t, b2, sched_e, sched_row, total_tiles, P, pair_token);
    combine_moe<<<N_TOK, 256, 0, stream>>>(P, tk_w, out);
}

// Round 5
// 650.752 us; speedup vs baseline: 1.0635x; 1.0635x over previous
//
#include <hip/hip_runtime.h>

#define N_TOK 8192
#define DIM   1024
#define HID   2048
#define NEXP  8
#define TOPK  2
#define BM 256
#define BN 256
#define BK 64
#define NTHREADS 512
#define MAXROWS (N_TOK*TOPK + NEXP*BM)   /* 18432 */
#define MAXRT   (MAXROWS/BM)             /* 72 row tiles */
#define NT_COL  (HID/BN)                 /* 8 col tiles */

typedef float f32x4 __attribute__((ext_vector_type(4)));
typedef short bf16x8 __attribute__((ext_vector_type(8)));

static __device__ __forceinline__ unsigned short f2bf(float f){
    union { float f; unsigned u; } v; v.f = f;
    unsigned r = v.u + 0x7FFFu + ((v.u >> 16) & 1u);
    return (unsigned short)(r >> 16);
}
static __device__ __forceinline__ float bf2f(unsigned short u){
    union { unsigned u; float f; } v; v.u = ((unsigned)u) << 16;
    return v.f;
}

static __device__ __forceinline__ void gload_lds16(const void* g, void* l){
    __builtin_amdgcn_global_load_lds((const __attribute__((address_space(1))) void*)g,
                                     (__attribute__((address_space(3))) void*)l,
                                     16, 0, 0);
}

// ---------------- weight convert + transpose (coalesced):
// src [z][R][C] f32 -> dst [z][C][R] bf16; 64x64 tiles
__global__ __launch_bounds__(256) void cvt_transpose_moe(
    const float* __restrict__ src, unsigned short* __restrict__ dst, int R, int C)
{
    __shared__ float tile[64][65];
    const size_t plane = (size_t)R * C;
    const float* s = src + (size_t)blockIdx.z * plane;
    unsigned short* d = dst + (size_t)blockIdx.z * plane;
    const int c0 = blockIdx.x * 64, r0 = blockIdx.y * 64;
    const int tq = threadIdx.x & 15, tr = threadIdx.x >> 4;   // 16 x 16
    #pragma unroll
    for (int p = 0; p < 4; ++p) {
        int row = p*16 + tr;
        float4 v = *(const float4*)(s + (size_t)(r0 + row) * C + c0 + tq*4);
        tile[row][tq*4+0] = v.x; tile[row][tq*4+1] = v.y;
        tile[row][tq*4+2] = v.z; tile[row][tq*4+3] = v.w;
    }
    __syncthreads();
    #pragma unroll
    for (int p = 0; p < 4; ++p) {
        int orow = p*16 + tr;
        ushort4 o;
        o.x = f2bf(tile[tq*4+0][orow]);
        o.y = f2bf(tile[tq*4+1][orow]);
        o.z = f2bf(tile[tq*4+2][orow]);
        o.w = f2bf(tile[tq*4+3][orow]);
        *(ushort4*)(d + (size_t)(c0 + orow) * R + r0 + tq*4) = o;
    }
}

// ---------------- router: 1 wave per token
__global__ __launch_bounds__(256) void router_moe(
    const float* __restrict__ x, const float* __restrict__ Wg, const float* __restrict__ bg,
    float* __restrict__ gate_probs, float* __restrict__ gate_mask,
    int* __restrict__ tk_e, float* __restrict__ tk_w, int* __restrict__ counts)
{
    const int lane = threadIdx.x & 63;
    const int n = blockIdx.x * 4 + (threadIdx.x >> 6);
    const float* xr = x + (size_t)n * DIM;

    float acc[NEXP];
    #pragma unroll
    for (int e = 0; e < NEXP; ++e) acc[e] = 0.f;
    #pragma unroll 4
    for (int i = 0; i < DIM/64; ++i) {
        int d = i*64 + lane;
        float xv = xr[d];
        const float4* wrow = (const float4*)(Wg + (size_t)d * NEXP);
        float4 w0 = wrow[0], w1 = wrow[1];
        acc[0] += xv*w0.x; acc[1] += xv*w0.y; acc[2] += xv*w0.z; acc[3] += xv*w0.w;
        acc[4] += xv*w1.x; acc[5] += xv*w1.y; acc[6] += xv*w1.z; acc[7] += xv*w1.w;
    }
    #pragma unroll
    for (int off = 32; off > 0; off >>= 1) {
        #pragma unroll
        for (int e = 0; e < NEXP; ++e) acc[e] += __shfl_xor(acc[e], off, 64);
    }
    float lgt[NEXP];
    float mx = acc[0] + bg[0];
    #pragma unroll
    for (int e = 0; e < NEXP; ++e) { lgt[e] = acc[e] + bg[e]; mx = fmaxf(mx, lgt[e]); }
    float s = 0.f;
    #pragma unroll
    for (int e = 0; e < NEXP; ++e) { lgt[e] = expf(lgt[e] - mx); s += lgt[e]; }
    float inv = 1.f / s;
    #pragma unroll
    for (int e = 0; e < NEXP; ++e) lgt[e] *= inv;

    int i1 = 0;
    #pragma unroll
    for (int e = 1; e < NEXP; ++e) if (lgt[e] > lgt[i1]) i1 = e;
    int i2 = (i1 == 0) ? 1 : 0;
    #pragma unroll
    for (int e = 0; e < NEXP; ++e) if (e != i1 && lgt[e] > lgt[i2]) i2 = e;
    float wsum = lgt[i1] + lgt[i2] + 1e-8f;
    float w1n = lgt[i1] / wsum, w2n = lgt[i2] / wsum;

    if (lane < NEXP) {
        gate_probs[(size_t)n*NEXP + lane] = lgt[lane];
        gate_mask [(size_t)n*NEXP + lane] = (lane == i1) ? w1n : (lane == i2) ? w2n : 0.f;
    }
    if (lane == 0) {
        tk_e[n*TOPK]   = i1; tk_e[n*TOPK+1] = i2;
        tk_w[n*TOPK]   = w1n; tk_w[n*TOPK+1] = w2n;
        atomicAdd(&counts[i1], 1);
        atomicAdd(&counts[i2], 1);
    }
}

// ---------------- scan
__global__ void scan_moe(const int* __restrict__ counts, int* __restrict__ bases,
                         int* __restrict__ cursors, int* __restrict__ sched_e,
                         int* __restrict__ sched_row, int* __restrict__ total_tiles)
{
    if (threadIdx.x != 0 || blockIdx.x != 0) return;
    int base = 0, t = 0;
    for (int e = 0; e < NEXP; ++e) {
        bases[e] = base; cursors[e] = 0;
        int nt = (counts[e] + BM - 1) / BM;
        for (int i = 0; i < nt; ++i) { sched_e[t] = e; sched_row[t] = base + i*BM; ++t; }
        base += nt * BM;
    }
    *total_tiles = t;
}

// ---------------- gather
__global__ __launch_bounds__(256) void gather_moe(
    const float* __restrict__ x, const int* __restrict__ tk_e,
    const int* __restrict__ bases, int* __restrict__ cursors,
    unsigned short* __restrict__ Xg, int* __restrict__ pair_token)
{
    __shared__ int rows_s[TOPK];
    const int n = blockIdx.x;
    if (threadIdx.x < TOPK) {
        int e = tk_e[n*TOPK + threadIdx.x];
        int slot = atomicAdd(&cursors[e], 1);
        int r = bases[e] + slot;
        rows_s[threadIdx.x] = r;
        pair_token[r] = n*2 + threadIdx.x;
    }
    __syncthreads();
    float4 xv = ((const float4*)(x + (size_t)n * DIM))[threadIdx.x];
    ushort4 b;
    b.x = f2bf(xv.x); b.y = f2bf(xv.y); b.z = f2bf(xv.z); b.w = f2bf(xv.w);
    #pragma unroll
    for (int kk = 0; kk < TOPK; ++kk)
        ((ushort4*)(Xg + (size_t)rows_s[kk] * DIM))[threadIdx.x] = b;
}

// ---------------- grouped GEMM: 256x256, BK=64, 8 waves, m201-style 8-phase schedule.
// LDS halves interleaved by quadrant bit: A-half = bit6 of row, B-half = bit5 of col.
// MODE 0: Out = relu(A @ Bt^T + bias) -> bf16 rows (Hb)
// MODE 1: P[pair] = A @ Bt^T + bias   -> bf16 token-slot scatter
#define PHASE_MFMA(MH, NH, BF) do {                                          \
    __builtin_amdgcn_s_setprio(1);                                           \
    _Pragma("unroll")                                                        \
    for (int mi = 0; mi < 4; ++mi)                                           \
        _Pragma("unroll")                                                    \
        for (int nb = 0; nb < 2; ++nb)                                       \
            _Pragma("unroll")                                                \
            for (int kk = 0; kk < 2; ++kk)                                   \
                acc[(MH)*4+mi][(NH)*2+nb] =                                  \
                    __builtin_amdgcn_mfma_f32_16x16x32_bf16(                 \
                        af[mi][kk], BF[nb][kk], acc[(MH)*4+mi][(NH)*2+nb],   \
                        0, 0, 0);                                            \
    __builtin_amdgcn_s_setprio(0);                                           \
} while (0)

template<int K, int MODE>
__global__ __launch_bounds__(512, 1) void gemm_moe(
    const unsigned short* __restrict__ A,    // [rows][K] bf16
    const unsigned short* __restrict__ Bt,   // [E][HID][K] bf16
    const float* __restrict__ bias,          // [E][HID]
    const int* __restrict__ sched_e, const int* __restrict__ sched_row,
    const int* __restrict__ total_tiles,
    unsigned short* __restrict__ Out,
    const int* __restrict__ pair_token)
{
    // T1: bijective XCD swizzle (576 % 8 == 0)
    const int nwg  = gridDim.x * gridDim.y;
    const int orig = blockIdx.y * gridDim.x + blockIdx.x;
    const int q = nwg >> 3, r8 = nwg & 7, xcd = orig & 7, lin = orig >> 3;
    const int wg = (xcd < r8 ? xcd*(q+1) : r8*(q+1) + (xcd-r8)*q) + lin;
    const int rt = wg / NT_COL, ct = wg % NT_COL;
    if (rt >= *total_tiles) return;

    const int e    = sched_e[rt];
    const int row0 = sched_row[rt];
    const int col0 = ct * BN;
    const unsigned short* Be = Bt + (size_t)e * HID * K;

    __shared__ __align__(1024) char lds[131072];
    char* ldsA = lds;            // [2 buf][2 half][128 idx * 128 B] = 64 KB
    char* ldsB = lds + 65536;    // same

    const int tid  = threadIdx.x;
    const int wv   = tid >> 6, lane = tid & 63;
    const int wr   = wv >> 2,  wc   = wv & 3;      // 2 x 4 wave grid, wave out 128x64
    const int lrow = lane & 15, lg  = lane >> 4;
    const int sr   = lane >> 3, si  = lane & 7;
    const int gc16 = si ^ sr;                      // pre-swizzled global 16B slot (T2)

    const unsigned short* Ab = A  + (size_t)row0 * K + gc16 * 8;
    const unsigned short* Bb = Be + (size_t)col0 * K + gc16 * 8;

    f32x4 acc[8][4] = {};
    bf16x8 af[4][2], b0f[2][2], b1f[2][2];

    // stage one half-tile (16KB = 2 gloads/thread). A: row = (idx>>6)*128 + h*64 + (idx&63)
    auto STAGE_A = [&](int buf, int h, int t) {
        char* dst = ldsA + (buf*2 + h)*16384;
        #pragma unroll
        for (int j = 0; j < 2; ++j) {
            int c = wv*2 + j;
            int r = ((c>>3)<<7) + h*64 + ((c&7)<<3) + sr;
            gload_lds16(Ab + (size_t)r * K + t*BK, dst + c*1024);
        }
    };
    // B: col = (idx>>5)*64 + h*32 + (idx&31)
    auto STAGE_B = [&](int buf, int h, int t) {
        char* dst = ldsB + (buf*2 + h)*16384;
        #pragma unroll
        for (int j = 0; j < 2; ++j) {
            int c = wv*2 + j;
            int idx = c*8 + sr;
            int gcol = ((idx>>5)<<6) + h*32 + (idx&31);
            gload_lds16(Bb + (size_t)gcol * K + t*BK, dst + c*1024);
        }
    };
    auto RD_A = [&](int buf, int mh) {             // 8 ds_read_b128
        const char* base = ldsA + (buf*2 + mh)*16384;
        #pragma unroll
        for (int mi = 0; mi < 4; ++mi) {
            int idx = wr*64 + mi*16 + lrow;
            #pragma unroll
            for (int kk = 0; kk < 2; ++kk) {
                int s = (kk*4 + lg) ^ (idx & 7);
                af[mi][kk] = *(const bf16x8*)(base + idx*128 + s*16);
            }
        }
    };
    auto RD_B = [&](int buf, int nh, bf16x8 (*bf)[2]) {  // 4 ds_read_b128
        const char* base = ldsB + (buf*2 + nh)*16384;
        #pragma unroll
        for (int nb = 0; nb < 2; ++nb) {
            int idx = wc*32 + nb*16 + lrow;
            #pragma unroll
            for (int kk = 0; kk < 2; ++kk) {
                int s = (kk*4 + lg) ^ (idx & 7);
                bf[nb][kk] = *(const bf16x8*)(base + idx*128 + s*16);
            }
        }
    };
    auto BARRIER = [&]() {
        __builtin_amdgcn_sched_barrier(0);
        __builtin_amdgcn_s_barrier();
        __builtin_amdgcn_sched_barrier(0);
    };
    auto LGKM0 = [&]() {
        asm volatile("s_waitcnt lgkmcnt(0)" ::: "memory");
        __builtin_amdgcn_sched_barrier(0);
    };

    constexpr int NT = K / BK;          // K-tiles
    constexpr int NI = NT / 2;          // iterations (2 K-tiles each)
    static_assert(NT % 2 == 0, "even K-tiles required");

    // prologue: stream positions p2..p7 of virtual iter -1
    STAGE_A(0,0,0); STAGE_B(0,0,0); STAGE_A(0,1,0); STAGE_B(0,1,0);
    STAGE_A(1,0,1); STAGE_B(1,0,1);
    asm volatile("s_waitcnt vmcnt(4)" ::: "memory");
    BARRIER();

    for (int i = 0; i < NI; ++i) {
        const int ta = 2*i, tb = 2*i + 1;
        const bool pf = (i + 1 < NI);
        // ---- tile ta (buf0) ----
        // p0: Q(mh0,nh0)
        RD_A(0,0); RD_B(0,0,b0f);
        STAGE_A(1,1,tb);
        BARRIER(); LGKM0();
        PHASE_MFMA(0,0,b0f);
        BARRIER();
        // p1: Q(mh0,nh1)
        RD_B(0,1,b1f);
        STAGE_B(1,1,tb);
        BARRIER(); LGKM0();
        PHASE_MFMA(0,1,b1f);
        BARRIER();
        // p2: Q(mh1,nh0)
        RD_A(0,1);
        if (pf) STAGE_A(0,0,ta+2);
        BARRIER(); LGKM0();
        PHASE_MFMA(1,0,b0f);
        BARRIER();
        // p3: Q(mh1,nh1)  (no ds_reads)
        if (pf) STAGE_B(0,0,ta+2);
        BARRIER();
        PHASE_MFMA(1,1,b1f);
        // tile-boundary drain. LEDGER: with pf, 12 outstanding -> vmcnt(4)
        // completes buf1 halves {0,1} for tile tb (8 oldest). WITHOUT pf
        // (last iter), only 8 outstanding -> vmcnt(4) would leave buf1
        // half1 (staged p0/p1) IN FLIGHT while p5/p6 read it -> the round-4
        // race. Full drain on last iteration.
        if (pf) { asm volatile("s_waitcnt vmcnt(4)" ::: "memory"); }
        else    { asm volatile("s_waitcnt vmcnt(0)" ::: "memory"); }
        BARRIER();
        // ---- tile tb (buf1) ----
        // p4
        RD_A(1,0); RD_B(1,0,b0f);
        if (pf) STAGE_A(0,1,ta+2);
        BARRIER(); LGKM0();
        PHASE_MFMA(0,0,b0f);
        BARRIER();
        // p5
        RD_B(1,1,b1f);
        if (pf) STAGE_B(0,1,ta+2);
        BARRIER(); LGKM0();
        PHASE_MFMA(0,1,b1f);
        BARRIER();
        // p6
        RD_A(1,1);
        if (pf) STAGE_A(1,0,tb+2);
        BARRIER(); LGKM0();
        PHASE_MFMA(1,0,b0f);
        BARRIER();
        // p7
        if (pf) STAGE_B(1,0,tb+2);
        BARRIER();
        PHASE_MFMA(1,1,b1f);
        if (pf) { asm volatile("s_waitcnt vmcnt(4)" ::: "memory"); BARRIER(); }
        // last iter: no loads outstanding, no further LDS reads -> no drain needed
    }

    // epilogue: C/D layout col=lane&15, row=(lane>>4)*4+reg
    if constexpr (MODE == 0) {
        #pragma unroll
        for (int nb = 0; nb < 4; ++nb) {
            int col = col0 + wc*64 + nb*16 + lrow;
            float bv = bias[(size_t)e*HID + col];
            #pragma unroll
            for (int mb = 0; mb < 8; ++mb) {
                int rb = row0 + wr*128 + mb*16 + lg*4;
                #pragma unroll
                for (int j = 0; j < 4; ++j) {
                    float v = fmaxf(acc[mb][nb][j] + bv, 0.f);
                    Out[(size_t)(rb + j) * HID + col] = f2bf(v);
                }
            }
        }
    } else {
        float bv[4]; int cols[4];
        #pragma unroll
        for (int nb = 0; nb < 4; ++nb) {
            cols[nb] = col0 + wc*64 + nb*16 + lrow;
            bv[nb] = bias[(size_t)e*HID + cols[nb]];
        }
        #pragma unroll
        for (int mb = 0; mb < 8; ++mb) {
            #pragma unroll
            for (int j = 0; j < 4; ++j) {
                int r = row0 + wr*128 + mb*16 + lg*4 + j;
                int pair = pair_token[r];
                if (pair < 0) continue;
                size_t prow = (size_t)(pair & 1) * N_TOK + (pair >> 1);
                #pragma unroll
                for (int nb = 0; nb < 4; ++nb)
                    Out[prow * HID + cols[nb]] = f2bf(acc[mb][nb][j] + bv[nb]);
            }
        }
    }
}

// ---------------- combine: out[n] = w0*P[0][n] + w1*P[1][n]
__global__ __launch_bounds__(256) void combine_moe(
    const unsigned short* __restrict__ P, const float* __restrict__ tk_w,
    float* __restrict__ out)
{
    const int n = blockIdx.x;
    const float w0 = tk_w[n*2], w1 = tk_w[n*2+1];
    const int c = threadIdx.x * 8;
    bf16x8 a = *(const bf16x8*)(P + (size_t)n * HID + c);
    bf16x8 b = *(const bf16x8*)(P + (size_t)(N_TOK + n) * HID + c);
    float4 o0, o1;
    float* op = &o0.x;
    #pragma unroll
    for (int i = 0; i < 4; ++i)
        op[i] = w0 * bf2f((unsigned short)a[i]) + w1 * bf2f((unsigned short)b[i]);
    float* op1 = &o1.x;
    #pragma unroll
    for (int i = 0; i < 4; ++i)
        op1[i] = w0 * bf2f((unsigned short)a[4+i]) + w1 * bf2f((unsigned short)b[4+i]);
    float4* dst = (float4*)(out + (size_t)n * HID + c);
    dst[0] = o0; dst[1] = o1;
}

extern "C" void kernel_launch(void* const* d_in, const int* in_sizes, int n_in,
                              void* d_out, int out_size, void* d_ws, size_t ws_size,
                              hipStream_t stream)
{
    const float* x  = (const float*)d_in[0];
    const float* Wg = (const float*)d_in[1];
    const float* bg = (const float*)d_in[2];
    const float* W1 = (const float*)d_in[3];
    const float* b1 = (const float*)d_in[4];
    const float* W2 = (const float*)d_in[5];
    const float* b2 = (const float*)d_in[6];

    float* out        = (float*)d_out;                       // [N, HID]
    float* gate_probs = out + (size_t)N_TOK * HID;           // [N, E]
    float* gate_mask  = gate_probs + (size_t)N_TOK * NEXP;   // [N, E]

    // workspace carve; P aliases dead W1t+Xg after GEMM1
    char* p = (char*)d_ws;
    auto carve = [&](size_t bytes) { char* r = p; p += (bytes + 255) & ~(size_t)255; return r; };
    unsigned short* W2t = (unsigned short*)carve((size_t)NEXP*HID*HID*2);  // 64 MB [e][j][h]
    unsigned short* Hb  = (unsigned short*)carve((size_t)MAXROWS*HID*2);   // 72 MB
    unsigned short* W1t = (unsigned short*)carve((size_t)NEXP*DIM*HID*2);  // 32 MB [e][h][d]
    unsigned short* Xg  = (unsigned short*)carve((size_t)MAXROWS*DIM*2);   // 36 MB
    unsigned short* P   = W1t;   // 64 MB alias over W1t+Xg; both dead at GEMM2
    int*   pair_token = (int*)  carve((size_t)MAXROWS*4);
    int*   tk_e       = (int*)  carve((size_t)N_TOK*TOPK*4);
    float* tk_w       = (float*)carve((size_t)N_TOK*TOPK*4);
    int*   counts     = (int*)  carve(256);
    int*   bases      = (int*)  carve(256);
    int*   cursors    = (int*)  carve(256);
    int*   sched_e    = (int*)  carve(1024);
    int*   sched_row  = (int*)  carve(1024);
    int*   total_tiles= (int*)  carve(256);

    hipMemsetAsync(counts, 0, 256, stream);
    hipMemsetAsync(pair_token, 0xFF, (size_t)MAXROWS*4, stream);  // -1 = pad

    cvt_transpose_moe<<<dim3(HID/64, DIM/64, NEXP), 256, 0, stream>>>(W1, W1t, DIM, HID);
    cvt_transpose_moe<<<dim3(HID/64, HID/64, NEXP), 256, 0, stream>>>(W2, W2t, HID, HID);
    router_moe<<<N_TOK/4, 256, 0, stream>>>(x, Wg, bg, gate_probs, gate_mask, tk_e, tk_w, counts);
    scan_moe<<<1, 64, 0, stream>>>(counts, bases, cursors, sched_e, sched_row, total_tiles);
    gather_moe<<<N_TOK, 256, 0, stream>>>(x, tk_e, bases, cursors, Xg, pair_token);
    gemm_moe<DIM, 0><<<dim3(MAXRT, NT_COL), NTHREADS, 0, stream>>>(
        Xg, W1t, b1, sched_e, sched_row, total_tiles, Hb, nullptr);
    gemm_moe<HID, 1><<<dim3(MAXRT, NT_COL), NTHREADS, 0, stream>>>(
        Hb, W2t, b2, sched_e, sched_row, total_tiles, P, pair_token);
    combine_moe<<<N_TOK, 256, 0, stream>>>(P, tk_w, out);
}

// Round 6
// 398.488 us; speedup vs baseline: 1.7368x; 1.6331x over previous
//
#include <hip/hip_runtime.h>

#define N_TOK 8192
#define DIM   1024
#define HID   2048
#define NEXP  8
#define TOPK  2
#define BM 256
#define BN 256
#define BK 64
#define NTHREADS 512
#define MAXROWS (N_TOK*TOPK + NEXP*BM)   /* 18432 */
#define MAXRT   (MAXROWS/BM)             /* 72 row tiles */
#define NT_COL  (HID/BN)                 /* 8 col tiles */
#define NPAIR   (N_TOK*TOPK)             /* 16384 */

typedef float f32x4 __attribute__((ext_vector_type(4)));
typedef short bf16x8 __attribute__((ext_vector_type(8)));

static __device__ __forceinline__ unsigned short f2bf(float f){
    union { float f; unsigned u; } v; v.f = f;
    unsigned r = v.u + 0x7FFFu + ((v.u >> 16) & 1u);
    return (unsigned short)(r >> 16);
}
static __device__ __forceinline__ float bf2f(unsigned short u){
    union { unsigned u; float f; } v; v.u = ((unsigned)u) << 16;
    return v.f;
}

static __device__ __forceinline__ void gload_lds16(const void* g, void* l){
    __builtin_amdgcn_global_load_lds((const __attribute__((address_space(1))) void*)g,
                                     (__attribute__((address_space(3))) void*)l,
                                     16, 0, 0);
}

// ---------------- weight convert + transpose (coalesced):
// src [z][R][C] f32 -> dst [z][C][R] bf16; 64x64 tiles
__global__ __launch_bounds__(256) void cvt_transpose_moe(
    const float* __restrict__ src, unsigned short* __restrict__ dst, int R, int C)
{
    __shared__ float tile[64][65];
    const size_t plane = (size_t)R * C;
    const float* s = src + (size_t)blockIdx.z * plane;
    unsigned short* d = dst + (size_t)blockIdx.z * plane;
    const int c0 = blockIdx.x * 64, r0 = blockIdx.y * 64;
    const int tq = threadIdx.x & 15, tr = threadIdx.x >> 4;   // 16 x 16
    #pragma unroll
    for (int p = 0; p < 4; ++p) {
        int row = p*16 + tr;
        float4 v = *(const float4*)(s + (size_t)(r0 + row) * C + c0 + tq*4);
        tile[row][tq*4+0] = v.x; tile[row][tq*4+1] = v.y;
        tile[row][tq*4+2] = v.z; tile[row][tq*4+3] = v.w;
    }
    __syncthreads();
    #pragma unroll
    for (int p = 0; p < 4; ++p) {
        int orow = p*16 + tr;
        ushort4 o;
        o.x = f2bf(tile[tq*4+0][orow]);
        o.y = f2bf(tile[tq*4+1][orow]);
        o.z = f2bf(tile[tq*4+2][orow]);
        o.w = f2bf(tile[tq*4+3][orow]);
        *(ushort4*)(d + (size_t)(c0 + orow) * R + r0 + tq*4) = o;
    }
}

// ---------------- router: 1 wave per token (NO atomics)
__global__ __launch_bounds__(256) void router_moe(
    const float* __restrict__ x, const float* __restrict__ Wg, const float* __restrict__ bg,
    float* __restrict__ gate_probs, float* __restrict__ gate_mask,
    int* __restrict__ tk_e, float* __restrict__ tk_w)
{
    const int lane = threadIdx.x & 63;
    const int n = blockIdx.x * 4 + (threadIdx.x >> 6);
    const float* xr = x + (size_t)n * DIM;

    float acc[NEXP];
    #pragma unroll
    for (int e = 0; e < NEXP; ++e) acc[e] = 0.f;
    #pragma unroll 4
    for (int i = 0; i < DIM/64; ++i) {
        int d = i*64 + lane;
        float xv = xr[d];
        const float4* wrow = (const float4*)(Wg + (size_t)d * NEXP);
        float4 w0 = wrow[0], w1 = wrow[1];
        acc[0] += xv*w0.x; acc[1] += xv*w0.y; acc[2] += xv*w0.z; acc[3] += xv*w0.w;
        acc[4] += xv*w1.x; acc[5] += xv*w1.y; acc[6] += xv*w1.z; acc[7] += xv*w1.w;
    }
    #pragma unroll
    for (int off = 32; off > 0; off >>= 1) {
        #pragma unroll
        for (int e = 0; e < NEXP; ++e) acc[e] += __shfl_xor(acc[e], off, 64);
    }
    float lgt[NEXP];
    float mx = acc[0] + bg[0];
    #pragma unroll
    for (int e = 0; e < NEXP; ++e) { lgt[e] = acc[e] + bg[e]; mx = fmaxf(mx, lgt[e]); }
    float s = 0.f;
    #pragma unroll
    for (int e = 0; e < NEXP; ++e) { lgt[e] = expf(lgt[e] - mx); s += lgt[e]; }
    float inv = 1.f / s;
    #pragma unroll
    for (int e = 0; e < NEXP; ++e) lgt[e] *= inv;

    int i1 = 0;
    #pragma unroll
    for (int e = 1; e < NEXP; ++e) if (lgt[e] > lgt[i1]) i1 = e;
    int i2 = (i1 == 0) ? 1 : 0;
    #pragma unroll
    for (int e = 0; e < NEXP; ++e) if (e != i1 && lgt[e] > lgt[i2]) i2 = e;
    float wsum = lgt[i1] + lgt[i2] + 1e-8f;
    float w1n = lgt[i1] / wsum, w2n = lgt[i2] / wsum;

    if (lane < NEXP) {
        gate_probs[(size_t)n*NEXP + lane] = lgt[lane];
        gate_mask [(size_t)n*NEXP + lane] = (lane == i1) ? w1n : (lane == i2) ? w2n : 0.f;
    }
    if (lane == 0) {
        tk_e[n*TOPK]   = i1; tk_e[n*TOPK+1] = i2;
        tk_w[n*TOPK]   = w1n; tk_w[n*TOPK+1] = w2n;
    }
}

// ---------------- assign: single block, 16 waves. Ballot-histogram + stable
// slot assignment for all NPAIR (token,slot) pairs. Replaces counts/cursors
// atomics and scan_moe. Also writes pair_token and the tile schedule.
__global__ __launch_bounds__(1024) void assign_moe(
    const int* __restrict__ tk_e,
    int* __restrict__ slot_row, int* __restrict__ pair_token,
    int* __restrict__ sched_e, int* __restrict__ sched_row,
    int* __restrict__ total_tiles)
{
    __shared__ int whist[16][NEXP];
    __shared__ int wbase[16][NEXP];
    const int w = threadIdx.x >> 6, lane = threadIdx.x & 63;
    const int PW = NPAIR / 16;                 // 1024 entries per wave
    const unsigned long long below = ((unsigned long long)1 << lane) - 1;

    // phase 1: per-wave histogram (all lanes redundantly popcount)
    int h[NEXP] = {0,0,0,0,0,0,0,0};
    for (int i = 0; i < PW/64; ++i) {
        int e = tk_e[w*PW + i*64 + lane];
        #pragma unroll
        for (int ee = 0; ee < NEXP; ++ee)
            h[ee] += __popcll(__ballot(e == ee));
    }
    if (lane == 0) {
        #pragma unroll
        for (int ee = 0; ee < NEXP; ++ee) whist[w][ee] = h[ee];
    }
    __syncthreads();

    // phase 2: one thread builds expert bases, per-wave bases, tile schedule
    if (threadIdx.x == 0) {
        int base = 0, t = 0, ebase[NEXP];
        for (int e = 0; e < NEXP; ++e) {
            int c = 0;
            for (int ww = 0; ww < 16; ++ww) c += whist[ww][e];
            ebase[e] = base;
            int nt = (c + BM - 1) / BM;
            for (int i = 0; i < nt; ++i) { sched_e[t] = e; sched_row[t] = base + i*BM; ++t; }
            base += nt * BM;
        }
        *total_tiles = t;
        for (int e = 0; e < NEXP; ++e) {
            int r = ebase[e];
            for (int ww = 0; ww < 16; ++ww) { wbase[ww][e] = r; r += whist[ww][e]; }
        }
    }
    __syncthreads();

    // phase 3: stable rank within expert -> slot
    int run[NEXP];
    #pragma unroll
    for (int ee = 0; ee < NEXP; ++ee) run[ee] = wbase[w][ee];
    for (int i = 0; i < PW/64; ++i) {
        int idx = w*PW + i*64 + lane;
        int e = tk_e[idx];
        int myslot = 0;
        #pragma unroll
        for (int ee = 0; ee < NEXP; ++ee) {
            unsigned long long m = __ballot(e == ee);
            if (e == ee) myslot = run[ee] + __popcll(m & below);
            run[ee] += __popcll(m);
        }
        slot_row[idx] = myslot;
        pair_token[myslot] = idx;
    }
}

// ---------------- gather: pure copy, slots precomputed
__global__ __launch_bounds__(256) void gather_moe(
    const float* __restrict__ x, const int* __restrict__ slot_row,
    unsigned short* __restrict__ Xg)
{
    const int n = blockIdx.x;
    const int r0 = slot_row[n*TOPK], r1 = slot_row[n*TOPK+1];
    float4 xv = ((const float4*)(x + (size_t)n * DIM))[threadIdx.x];
    ushort4 b;
    b.x = f2bf(xv.x); b.y = f2bf(xv.y); b.z = f2bf(xv.z); b.w = f2bf(xv.w);
    ((ushort4*)(Xg + (size_t)r0 * DIM))[threadIdx.x] = b;
    ((ushort4*)(Xg + (size_t)r1 * DIM))[threadIdx.x] = b;
}

// ---------------- grouped GEMM: 256x256, BK=64, 8 waves, m201-style 8-phase schedule.
// (unchanged from round 5 — passed, GEMMs out of top-5)
#define PHASE_MFMA(MH, NH, BF) do {                                          \
    __builtin_amdgcn_s_setprio(1);                                           \
    _Pragma("unroll")                                                        \
    for (int mi = 0; mi < 4; ++mi)                                           \
        _Pragma("unroll")                                                    \
        for (int nb = 0; nb < 2; ++nb)                                       \
            _Pragma("unroll")                                                \
            for (int kk = 0; kk < 2; ++kk)                                   \
                acc[(MH)*4+mi][(NH)*2+nb] =                                  \
                    __builtin_amdgcn_mfma_f32_16x16x32_bf16(                 \
                        af[mi][kk], BF[nb][kk], acc[(MH)*4+mi][(NH)*2+nb],   \
                        0, 0, 0);                                            \
    __builtin_amdgcn_s_setprio(0);                                           \
} while (0)

template<int K, int MODE>
__global__ __launch_bounds__(512, 1) void gemm_moe(
    const unsigned short* __restrict__ A,    // [rows][K] bf16
    const unsigned short* __restrict__ Bt,   // [E][HID][K] bf16
    const float* __restrict__ bias,          // [E][HID]
    const int* __restrict__ sched_e, const int* __restrict__ sched_row,
    const int* __restrict__ total_tiles,
    unsigned short* __restrict__ Out,
    const int* __restrict__ pair_token)
{
    // T1: bijective XCD swizzle (576 % 8 == 0)
    const int nwg  = gridDim.x * gridDim.y;
    const int orig = blockIdx.y * gridDim.x + blockIdx.x;
    const int q = nwg >> 3, r8 = nwg & 7, xcd = orig & 7, lin = orig >> 3;
    const int wg = (xcd < r8 ? xcd*(q+1) : r8*(q+1) + (xcd-r8)*q) + lin;
    const int rt = wg / NT_COL, ct = wg % NT_COL;
    if (rt >= *total_tiles) return;

    const int e    = sched_e[rt];
    const int row0 = sched_row[rt];
    const int col0 = ct * BN;
    const unsigned short* Be = Bt + (size_t)e * HID * K;

    __shared__ __align__(1024) char lds[131072];
    char* ldsA = lds;            // [2 buf][2 half][128 idx * 128 B] = 64 KB
    char* ldsB = lds + 65536;    // same

    const int tid  = threadIdx.x;
    const int wv   = tid >> 6, lane = tid & 63;
    const int wr   = wv >> 2,  wc   = wv & 3;      // 2 x 4 wave grid, wave out 128x64
    const int lrow = lane & 15, lg  = lane >> 4;
    const int sr   = lane >> 3, si  = lane & 7;
    const int gc16 = si ^ sr;                      // pre-swizzled global 16B slot (T2)

    const unsigned short* Ab = A  + (size_t)row0 * K + gc16 * 8;
    const unsigned short* Bb = Be + (size_t)col0 * K + gc16 * 8;

    f32x4 acc[8][4] = {};
    bf16x8 af[4][2], b0f[2][2], b1f[2][2];

    auto STAGE_A = [&](int buf, int h, int t) {
        char* dst = ldsA + (buf*2 + h)*16384;
        #pragma unroll
        for (int j = 0; j < 2; ++j) {
            int c = wv*2 + j;
            int r = ((c>>3)<<7) + h*64 + ((c&7)<<3) + sr;
            gload_lds16(Ab + (size_t)r * K + t*BK, dst + c*1024);
        }
    };
    auto STAGE_B = [&](int buf, int h, int t) {
        char* dst = ldsB + (buf*2 + h)*16384;
        #pragma unroll
        for (int j = 0; j < 2; ++j) {
            int c = wv*2 + j;
            int idx = c*8 + sr;
            int gcol = ((idx>>5)<<6) + h*32 + (idx&31);
            gload_lds16(Bb + (size_t)gcol * K + t*BK, dst + c*1024);
        }
    };
    auto RD_A = [&](int buf, int mh) {             // 8 ds_read_b128
        const char* base = ldsA + (buf*2 + mh)*16384;
        #pragma unroll
        for (int mi = 0; mi < 4; ++mi) {
            int idx = wr*64 + mi*16 + lrow;
            #pragma unroll
            for (int kk = 0; kk < 2; ++kk) {
                int s = (kk*4 + lg) ^ (idx & 7);
                af[mi][kk] = *(const bf16x8*)(base + idx*128 + s*16);
            }
        }
    };
    auto RD_B = [&](int buf, int nh, bf16x8 (*bf)[2]) {  // 4 ds_read_b128
        const char* base = ldsB + (buf*2 + nh)*16384;
        #pragma unroll
        for (int nb = 0; nb < 2; ++nb) {
            int idx = wc*32 + nb*16 + lrow;
            #pragma unroll
            for (int kk = 0; kk < 2; ++kk) {
                int s = (kk*4 + lg) ^ (idx & 7);
                bf[nb][kk] = *(const bf16x8*)(base + idx*128 + s*16);
            }
        }
    };
    auto BARRIER = [&]() {
        __builtin_amdgcn_sched_barrier(0);
        __builtin_amdgcn_s_barrier();
        __builtin_amdgcn_sched_barrier(0);
    };
    auto LGKM0 = [&]() {
        asm volatile("s_waitcnt lgkmcnt(0)" ::: "memory");
        __builtin_amdgcn_sched_barrier(0);
    };

    constexpr int NT = K / BK;          // K-tiles
    constexpr int NI = NT / 2;          // iterations (2 K-tiles each)
    static_assert(NT % 2 == 0, "even K-tiles required");

    // prologue: stream positions p2..p7 of virtual iter -1
    STAGE_A(0,0,0); STAGE_B(0,0,0); STAGE_A(0,1,0); STAGE_B(0,1,0);
    STAGE_A(1,0,1); STAGE_B(1,0,1);
    asm volatile("s_waitcnt vmcnt(4)" ::: "memory");
    BARRIER();

    for (int i = 0; i < NI; ++i) {
        const int ta = 2*i, tb = 2*i + 1;
        const bool pf = (i + 1 < NI);
        // ---- tile ta (buf0) ----
        RD_A(0,0); RD_B(0,0,b0f);
        STAGE_A(1,1,tb);
        BARRIER(); LGKM0();
        PHASE_MFMA(0,0,b0f);
        BARRIER();
        RD_B(0,1,b1f);
        STAGE_B(1,1,tb);
        BARRIER(); LGKM0();
        PHASE_MFMA(0,1,b1f);
        BARRIER();
        RD_A(0,1);
        if (pf) STAGE_A(0,0,ta+2);
        BARRIER(); LGKM0();
        PHASE_MFMA(1,0,b0f);
        BARRIER();
        if (pf) STAGE_B(0,0,ta+2);
        BARRIER();
        PHASE_MFMA(1,1,b1f);
        // tile-boundary drain. LEDGER: with pf, 12 outstanding -> vmcnt(4)
        // completes buf1 halves {0,1} for tile tb. Last iter: only 8
        // outstanding -> full drain (round-4 race fix).
        if (pf) { asm volatile("s_waitcnt vmcnt(4)" ::: "memory"); }
        else    { asm volatile("s_waitcnt vmcnt(0)" ::: "memory"); }
        BARRIER();
        // ---- tile tb (buf1) ----
        RD_A(1,0); RD_B(1,0,b0f);
        if (pf) STAGE_A(0,1,ta+2);
        BARRIER(); LGKM0();
        PHASE_MFMA(0,0,b0f);
        BARRIER();
        RD_B(1,1,b1f);
        if (pf) STAGE_B(0,1,ta+2);
        BARRIER(); LGKM0();
        PHASE_MFMA(0,1,b1f);
        BARRIER();
        RD_A(1,1);
        if (pf) STAGE_A(1,0,tb+2);
        BARRIER(); LGKM0();
        PHASE_MFMA(1,0,b0f);
        BARRIER();
        if (pf) STAGE_B(1,0,tb+2);
        BARRIER();
        PHASE_MFMA(1,1,b1f);
        if (pf) { asm volatile("s_waitcnt vmcnt(4)" ::: "memory"); BARRIER(); }
    }

    // epilogue: C/D layout col=lane&15, row=(lane>>4)*4+reg
    if constexpr (MODE == 0) {
        #pragma unroll
        for (int nb = 0; nb < 4; ++nb) {
            int col = col0 + wc*64 + nb*16 + lrow;
            float bv = bias[(size_t)e*HID + col];
            #pragma unroll
            for (int mb = 0; mb < 8; ++mb) {
                int rb = row0 + wr*128 + mb*16 + lg*4;
                #pragma unroll
                for (int j = 0; j < 4; ++j) {
                    float v = fmaxf(acc[mb][nb][j] + bv, 0.f);
                    Out[(size_t)(rb + j) * HID + col] = f2bf(v);
                }
            }
        }
    } else {
        float bv[4]; int cols[4];
        #pragma unroll
        for (int nb = 0; nb < 4; ++nb) {
            cols[nb] = col0 + wc*64 + nb*16 + lrow;
            bv[nb] = bias[(size_t)e*HID + cols[nb]];
        }
        #pragma unroll
        for (int mb = 0; mb < 8; ++mb) {
            #pragma unroll
            for (int j = 0; j < 4; ++j) {
                int r = row0 + wr*128 + mb*16 + lg*4 + j;
                int pair = pair_token[r];
                if (pair < 0) continue;
                size_t prow = (size_t)(pair & 1) * N_TOK + (pair >> 1);
                #pragma unroll
                for (int nb = 0; nb < 4; ++nb)
                    Out[prow * HID + cols[nb]] = f2bf(acc[mb][nb][j] + bv[nb]);
            }
        }
    }
}

// ---------------- combine: out[n] = w0*P[0][n] + w1*P[1][n]
__global__ __launch_bounds__(256) void combine_moe(
    const unsigned short* __restrict__ P, const float* __restrict__ tk_w,
    float* __restrict__ out)
{
    const int n = blockIdx.x;
    const float w0 = tk_w[n*2], w1 = tk_w[n*2+1];
    const int c = threadIdx.x * 8;
    bf16x8 a = *(const bf16x8*)(P + (size_t)n * HID + c);
    bf16x8 b = *(const bf16x8*)(P + (size_t)(N_TOK + n) * HID + c);
    float4 o0, o1;
    float* op = &o0.x;
    #pragma unroll
    for (int i = 0; i < 4; ++i)
        op[i] = w0 * bf2f((unsigned short)a[i]) + w1 * bf2f((unsigned short)b[i]);
    float* op1 = &o1.x;
    #pragma unroll
    for (int i = 0; i < 4; ++i)
        op1[i] = w0 * bf2f((unsigned short)a[4+i]) + w1 * bf2f((unsigned short)b[4+i]);
    float4* dst = (float4*)(out + (size_t)n * HID + c);
    dst[0] = o0; dst[1] = o1;
}

extern "C" void kernel_launch(void* const* d_in, const int* in_sizes, int n_in,
                              void* d_out, int out_size, void* d_ws, size_t ws_size,
                              hipStream_t stream)
{
    const float* x  = (const float*)d_in[0];
    const float* Wg = (const float*)d_in[1];
    const float* bg = (const float*)d_in[2];
    const float* W1 = (const float*)d_in[3];
    const float* b1 = (const float*)d_in[4];
    const float* W2 = (const float*)d_in[5];
    const float* b2 = (const float*)d_in[6];

    float* out        = (float*)d_out;                       // [N, HID]
    float* gate_probs = out + (size_t)N_TOK * HID;           // [N, E]
    float* gate_mask  = gate_probs + (size_t)N_TOK * NEXP;   // [N, E]

    // workspace carve; P aliases dead W1t+Xg after GEMM1
    char* p = (char*)d_ws;
    auto carve = [&](size_t bytes) { char* r = p; p += (bytes + 255) & ~(size_t)255; return r; };
    unsigned short* W2t = (unsigned short*)carve((size_t)NEXP*HID*HID*2);  // 64 MB [e][j][h]
    unsigned short* Hb  = (unsigned short*)carve((size_t)MAXROWS*HID*2);   // 72 MB
    unsigned short* W1t = (unsigned short*)carve((size_t)NEXP*DIM*HID*2);  // 32 MB [e][h][d]
    unsigned short* Xg  = (unsigned short*)carve((size_t)MAXROWS*DIM*2);   // 36 MB
    unsigned short* P   = W1t;   // 64 MB alias over W1t+Xg; both dead at GEMM2
    int*   pair_token = (int*)  carve((size_t)MAXROWS*4);
    int*   slot_row   = (int*)  carve((size_t)NPAIR*4);
    int*   tk_e       = (int*)  carve((size_t)NPAIR*4);
    float* tk_w       = (float*)carve((size_t)NPAIR*4);
    int*   sched_e    = (int*)  carve(1024);
    int*   sched_row  = (int*)  carve(1024);
    int*   total_tiles= (int*)  carve(256);

    hipMemsetAsync(pair_token, 0xFF, (size_t)MAXROWS*4, stream);  // -1 = pad

    cvt_transpose_moe<<<dim3(HID/64, DIM/64, NEXP), 256, 0, stream>>>(W1, W1t, DIM, HID);
    cvt_transpose_moe<<<dim3(HID/64, HID/64, NEXP), 256, 0, stream>>>(W2, W2t, HID, HID);
    router_moe<<<N_TOK/4, 256, 0, stream>>>(x, Wg, bg, gate_probs, gate_mask, tk_e, tk_w);
    assign_moe<<<1, 1024, 0, stream>>>(tk_e, slot_row, pair_token,
                                       sched_e, sched_row, total_tiles);
    gather_moe<<<N_TOK, 256, 0, stream>>>(x, slot_row, Xg);
    gemm_moe<DIM, 0><<<dim3(MAXRT, NT_COL), NTHREADS, 0, stream>>>(
        Xg, W1t, b1, sched_e, sched_row, total_tiles, Hb, nullptr);
    gemm_moe<HID, 1><<<dim3(MAXRT, NT_COL), NTHREADS, 0, stream>>>(
        Hb, W2t, b2, sched_e, sched_row, total_tiles, P, pair_token);
    combine_moe<<<N_TOK, 256, 0, stream>>>(P, tk_w, out);
}